// Round 4
// baseline (439.900 us; speedup 1.0000x reference)
//
#include <hip/hip_runtime.h>
#include <hip/hip_bf16.h>

// RolePositionBiasedAttention: B=16384, N=10, D=256, H=8, DH=32
// prep_wt (once) -> fused_all (QKV GEMM + attention + WO GEMM in one kernel;
// Z read once, out written once, nothing else touches HBM)

typedef __attribute__((ext_vector_type(8))) short bf16x8;
typedef __attribute__((ext_vector_type(4))) float f32x4;

__device__ __forceinline__ unsigned short f2bf(float f) {
  union { __hip_bfloat16 h; unsigned short u; } cv;
  cv.h = __float2bfloat16(f);
  return cv.u;
}
__device__ __forceinline__ float bflo(unsigned int u) { return __uint_as_float(u << 16); }
__device__ __forceinline__ float bfhi(unsigned int u) { return __uint_as_float(u & 0xffff0000u); }

// ---------------- prep: WT[w][n][k] = bf16(W[k][n]), w in {Q,K,V,O} ----------------
__global__ void prep_wt_kernel(const float* __restrict__ WQ, const float* __restrict__ WK,
                               const float* __restrict__ WV, const float* __restrict__ WO,
                               __hip_bfloat16* __restrict__ wt) {
  const int k = blockIdx.x;      // 0..255
  const int n = threadIdx.x;     // 0..255
  wt[0 * 65536 + n * 256 + k] = __float2bfloat16(WQ[k * 256 + n]);
  wt[1 * 65536 + n * 256 + k] = __float2bfloat16(WK[k * 256 + n]);
  wt[2 * 65536 + n * 256 + k] = __float2bfloat16(WV[k * 256 + n]);
  wt[3 * 65536 + n * 256 + k] = __float2bfloat16(WO[k * 256 + n]);
}

// ---------------- fused everything: block = 8 batches (80 rows), 256 threads ----------------
// LDS: As[80][512B]   Z-tile bf16, 16B chunks, chunk ^= row&7          (40960 B)
//      Sp[80][400B]   per-pass strip: q 0..127 | k 128..255 | v 256..383 bytes, each an
//                     8-chunk region with chunk ^= row&7               (32000 B)
//      roles[80], Bp[800]                                              (3520 B)
// Per pass p (head pair 2p,2p+1):
//   epi: acc_s -> strip | barrier | GEMM_QKV(p+1) [regs/As/L2 only] + attn(p) [strip only,
//   writes o over own q slot] | barrier | WO(p): acc_o += strip_q x WO slice | barrier
__global__ __launch_bounds__(256, 2) void fused_all_kernel(
    const float* __restrict__ Z, const __hip_bfloat16* __restrict__ wt,
    const int* __restrict__ roles, const float* __restrict__ Bp,
    float* __restrict__ out)
{
  __shared__ __align__(16) char lds[76480];
  char* As = lds;
  char* Sp = lds + 40960;
  int* roles_lds = (int*)(lds + 72960);
  float* Bp_lds = (float*)(lds + 73280);

  const int t = threadIdx.x;
  const int lane = t & 63;
  const int wv = t >> 6;
  const int g = lane >> 4, cx = lane & 15;
  const int blk = blockIdx.x;
  const size_t r0 = (size_t)blk * 80;

  if (t < 80) roles_lds[t] = roles[r0 + t];
  if (t < 200) ((float4*)Bp_lds)[t] = ((const float4*)Bp)[t];   // 800 floats = 200 float4

  // ---- stage Z tile -> As (fp32 -> bf16) ----
  #pragma unroll
  for (int c = 0; c < 10; ++c) {
    const int idx = c * 256 + t;            // (row, chunk) over 80x32
    const int row = idx >> 5, ch = idx & 31;
    const float* src = Z + (r0 + row) * 256 + ch * 8;
    float4 f0 = *(const float4*)(src);
    float4 f1 = *(const float4*)(src + 4);
    union { bf16x8 v; unsigned short u[8]; } pk;
    pk.u[0] = f2bf(f0.x); pk.u[1] = f2bf(f0.y);
    pk.u[2] = f2bf(f0.z); pk.u[3] = f2bf(f0.w);
    pk.u[4] = f2bf(f1.x); pk.u[5] = f2bf(f1.y);
    pk.u[6] = f2bf(f1.z); pk.u[7] = f2bf(f1.w);
    *(bf16x8*)(As + row * 512 + ((ch ^ (row & 7)) * 16)) = pk.v;
  }
  __syncthreads();

  f32x4 acc_o[5][4];
  #pragma unroll
  for (int a = 0; a < 5; ++a)
    #pragma unroll
    for (int b = 0; b < 4; ++b) acc_o[a][b] = (f32x4){0.f, 0.f, 0.f, 0.f};
  f32x4 acc_s[5][3];

  // ---- QKV strip GEMM for pass p: 80 x 192 (q|k|v for heads 2p,2p+1) ----
  auto gemm_qkv = [&](int p) {
    #pragma unroll
    for (int mi = 0; mi < 5; ++mi)
      #pragma unroll
      for (int nf = 0; nf < 3; ++nf) acc_s[mi][nf] = (f32x4){0.f, 0.f, 0.f, 0.f};
    const __hip_bfloat16* bptr[3];
    #pragma unroll
    for (int nf = 0; nf < 3; ++nf) {
      const int f = wv * 3 + nf;            // 0..11
      const int mf = f >> 2;                // 0=Q,1=K,2=V
      const int ncol = p * 64 + (f & 3) * 16;
      bptr[nf] = wt + mf * 65536 + (ncol + cx) * 256 + g * 8;
    }
    #pragma unroll
    for (int kk = 0; kk < 8; ++kk) {
      bf16x8 bfr[3];
      #pragma unroll
      for (int nf = 0; nf < 3; ++nf) bfr[nf] = *(const bf16x8*)(bptr[nf] + kk * 32);
      bf16x8 afr[5];
      #pragma unroll
      for (int mi = 0; mi < 5; ++mi) {
        const int row = mi * 16 + cx;
        const int ch = (kk * 4 + g) ^ (row & 7);
        afr[mi] = *(const bf16x8*)(As + row * 512 + ch * 16);
      }
      #pragma unroll
      for (int mi = 0; mi < 5; ++mi)
        #pragma unroll
        for (int nf = 0; nf < 3; ++nf)
          acc_s[mi][nf] = __builtin_amdgcn_mfma_f32_16x16x32_bf16(afr[mi], bfr[nf], acc_s[mi][nf], 0, 0, 0);
    }
  };

  auto epi = [&]() {
    #pragma unroll
    for (int mi = 0; mi < 5; ++mi)
      #pragma unroll
      for (int nf = 0; nf < 3; ++nf)
        #pragma unroll
        for (int jj = 0; jj < 4; ++jj) {
          const int row = mi * 16 + g * 4 + jj;
          const int col = wv * 48 + nf * 16 + cx;     // 0..191
          const int region = col >> 6;                // 0=q,1=k,2=v
          const int c = (col >> 3) & 7;
          *(unsigned short*)(Sp + row * 400 + region * 128 +
                             ((c ^ (row & 7)) * 16) + (col & 7) * 2) = f2bf(acc_s[mi][nf][jj]);
        }
  };

  auto attn = [&](int p) {
    const int b = t / 20, hh = (t / 10) % 2, i = t % 10;
    const int h = p * 2 + hh;
    const int lrow = b * 10 + i;
    float qf[32];
    #pragma unroll
    for (int c = 0; c < 4; ++c) {
      uint4 u = *(const uint4*)(Sp + lrow * 400 + (((hh * 4 + c) ^ (lrow & 7)) * 16));
      qf[c*8+0] = bflo(u.x); qf[c*8+1] = bfhi(u.x);
      qf[c*8+2] = bflo(u.y); qf[c*8+3] = bfhi(u.y);
      qf[c*8+4] = bflo(u.z); qf[c*8+5] = bfhi(u.z);
      qf[c*8+6] = bflo(u.w); qf[c*8+7] = bfhi(u.w);
    }
    const int ri = roles_lds[b * 10 + i];
    const float* brow = Bp_lds + h * 100 + ri * 10;
    float s[10];
    #pragma unroll
    for (int j = 0; j < 10; ++j) {
      const int kr = b * 10 + j;
      const char* kbase = Sp + kr * 400 + 128;
      float a = 0.f;
      #pragma unroll
      for (int c = 0; c < 4; ++c) {
        uint4 u = *(const uint4*)(kbase + (((hh * 4 + c) ^ (kr & 7)) * 16));
        a += qf[c*8+0]*bflo(u.x) + qf[c*8+1]*bfhi(u.x)
           + qf[c*8+2]*bflo(u.y) + qf[c*8+3]*bfhi(u.y)
           + qf[c*8+4]*bflo(u.z) + qf[c*8+5]*bfhi(u.z)
           + qf[c*8+6]*bflo(u.w) + qf[c*8+7]*bfhi(u.w);
      }
      s[j] = a * 0.17677669529663687f + brow[roles_lds[b * 10 + j]];
    }
    float mx = s[0];
    #pragma unroll
    for (int j = 1; j < 10; ++j) mx = fmaxf(mx, s[j]);
    float pr[10], sum = 0.f;
    #pragma unroll
    for (int j = 0; j < 10; ++j) { pr[j] = expf(s[j] - mx); sum += pr[j]; }
    const float inv = 1.f / sum;
    float o[32];
    #pragma unroll
    for (int d = 0; d < 32; ++d) o[d] = 0.f;
    #pragma unroll
    for (int j = 0; j < 10; ++j) {
      const float pj = pr[j] * inv;
      const int kr = b * 10 + j;
      const char* vbase = Sp + kr * 400 + 256;
      #pragma unroll
      for (int c = 0; c < 4; ++c) {
        uint4 u = *(const uint4*)(vbase + (((hh * 4 + c) ^ (kr & 7)) * 16));
        o[c*8+0] += pj * bflo(u.x); o[c*8+1] += pj * bfhi(u.x);
        o[c*8+2] += pj * bflo(u.y); o[c*8+3] += pj * bfhi(u.y);
        o[c*8+4] += pj * bflo(u.z); o[c*8+5] += pj * bfhi(u.z);
        o[c*8+6] += pj * bflo(u.w); o[c*8+7] += pj * bfhi(u.w);
      }
    }
    // write o over own q slot (attn_out for head h, row lrow)
    #pragma unroll
    for (int c = 0; c < 4; ++c) {
      uint4 u;
      u.x = (unsigned)f2bf(o[c*8+0]) | ((unsigned)f2bf(o[c*8+1]) << 16);
      u.y = (unsigned)f2bf(o[c*8+2]) | ((unsigned)f2bf(o[c*8+3]) << 16);
      u.z = (unsigned)f2bf(o[c*8+4]) | ((unsigned)f2bf(o[c*8+5]) << 16);
      u.w = (unsigned)f2bf(o[c*8+6]) | ((unsigned)f2bf(o[c*8+7]) << 16);
      *(uint4*)(Sp + lrow * 400 + (((hh * 4 + c) ^ (lrow & 7)) * 16)) = u;
    }
  };

  auto wo = [&](int p) {
    const __hip_bfloat16* WOT = wt + 3 * 65536;
    #pragma unroll
    for (int kk = 0; kk < 2; ++kk) {
      bf16x8 bw[4];
      #pragma unroll
      for (int nf = 0; nf < 4; ++nf) {
        const int n = wv * 64 + nf * 16 + cx;
        bw[nf] = *(const bf16x8*)(WOT + n * 256 + p * 64 + kk * 32 + g * 8);
      }
      bf16x8 aw[5];
      #pragma unroll
      for (int mi = 0; mi < 5; ++mi) {
        const int row = mi * 16 + cx;
        const int ch = (kk * 4 + g) ^ (row & 7);
        aw[mi] = *(const bf16x8*)(Sp + row * 400 + ch * 16);
      }
      #pragma unroll
      for (int mi = 0; mi < 5; ++mi)
        #pragma unroll
        for (int nf = 0; nf < 4; ++nf)
          acc_o[mi][nf] = __builtin_amdgcn_mfma_f32_16x16x32_bf16(aw[mi], bw[nf], acc_o[mi][nf], 0, 0, 0);
    }
  };

  gemm_qkv(0);
  #pragma unroll 1
  for (int p = 0; p < 4; ++p) {
    __syncthreads();                 // strip free (WO of p-1 done)
    epi();
    __syncthreads();                 // strip ready
    if (p < 3) gemm_qkv(p + 1);      // regs/As/L2 only — overlaps attn below
    if (t < 160) attn(p);            // strip only
    __syncthreads();                 // o ready
    wo(p);
  }

  // ---- final out epilogue (fp32, coalesced in 16-lane groups) ----
  #pragma unroll
  for (int mi = 0; mi < 5; ++mi)
    #pragma unroll
    for (int nf = 0; nf < 4; ++nf)
      #pragma unroll
      for (int jj = 0; jj < 4; ++jj) {
        const size_t row = r0 + mi * 16 + g * 4 + jj;
        const int col = wv * 64 + nf * 16 + cx;
        out[row * 256 + col] = acc_o[mi][nf][jj];
      }
}

extern "C" void kernel_launch(void* const* d_in, const int* in_sizes, int n_in,
                              void* d_out, int out_size, void* d_ws, size_t ws_size,
                              hipStream_t stream)
{
  const float* Z     = (const float*)d_in[0];
  const int*   roles = (const int*)d_in[1];
  const float* WQ    = (const float*)d_in[2];
  const float* WK    = (const float*)d_in[3];
  const float* WV    = (const float*)d_in[4];
  const float* WO    = (const float*)d_in[5];
  const float* Bp    = (const float*)d_in[6];
  float* out = (float*)d_out;

  __hip_bfloat16* wt = (__hip_bfloat16*)d_ws;   // 512 KiB

  prep_wt_kernel<<<256, 256, 0, stream>>>(WQ, WK, WV, WO, wt);
  fused_all_kernel<<<2048, 256, 0, stream>>>(Z, wt, roles, Bp, out);
}